// Round 19
// baseline (113.125 us; speedup 1.0000x reference)
//
#include <hip/hip_runtime.h>
#include <math.h>

#define PH 7
#define PW 7
#define B_ 4
#define C_ 256
#define H_ 50
#define W_ 50
#define R_ 256
#define S_ (H_ * W_)     // 2500
#define NCELL (PH * PW)  // 49
#define REP 3            // DIAGNOSTIC: repeat full work body so this kernel
                         // tops rocprof with counters. Stores idempotent.

// R18 pack4 kernel (measured ~30.8 us) with REP wrapper. Purpose: surface
// VALUBusy / OccupancyPercent / SQ_LDS_BANK_CONFLICT / FETCH_SIZE for the
// real steady-state kernel; bottom-up model says ~2-5 us, measured 30.8 —
// the 6-15x gap is (a) residency, (b) scalar bookkeeping issue, (c) reduce-
// phase LDS conflicts, or (d) cache-port serialization. Counters decide.
__global__ void __launch_bounds__(256, 8)
roi_pool_pack4(const float* __restrict__ features, const int* __restrict__ rois,
               float* __restrict__ out) {
    __shared__ float strip[4][PH][64];    // wave-private strips, 7168 B
    const int bx   = blockIdx.x;
    const int r    = bx >> 4;             // 0..255
    const int wid  = threadIdx.x >> 6;    // 0..3
    const int lane = threadIdx.x & 63;
    const int cw   = ((bx & 15) << 4) | (wid << 2);   // wave's 4-ch base

    const int* roi = rois + r * 5;        // r uniform -> scalar loads
    const int b  = roi[0];
    const int x1 = roi[1] >> 4;           // floor(v/16), v in [0,800)
    const int y1 = roi[2] >> 4;
    const int x2 = roi[3] >> 4;
    const int y2 = roi[4] >> 4;
    const int h = y2 - y1 + 1;            // 1..50
    const int w = x2 - x1 + 1;            // 1..50

    // adaptive packing (all wave-uniform scalars)
    const int npacksh = (w <= 16) ? 2 : (w <= 32) ? 1 : 0;
    const int npack   = 1 << npacksh;     // 4 / 2 / 1 channels per pass
    const int ncolsh  = 6 - npacksh;      // 16 / 32 / 64 cols per channel
    const int ncol    = 1 << ncolsh;
    const int passes  = 4 >> npacksh;     // 1 / 2 / 4

    const int hc   = lane >> ncolsh;      // sub-channel within pass
    const int col  = lane & (ncol - 1);
    const int xcol = x1 + min(col, w - 1);   // clamped dup: max-safe, merged

    // reduce-phase lane mapping (lanes 49..63 idle there)
    const int cell = (lane < NCELL) ? lane : NCELL - 1;
    const int p  = cell / PW;             // magic mul
    const int q  = cell - p * PW;
    const int swr  = (q * w) / PW;
    const int ewr  = ((q + 1) * w + PW - 1) / PW;
    const int kwm1 = ewr - swr - 1;       // >= 0
    const int kmax = w / PW + 2;          // scalar bound, covers all windows

    #pragma unroll 1
    for (int rep = 0; rep < REP; ++rep) {
        #pragma unroll 1
        for (int pi = 0; pi < passes; ++pi) {
            const int chb = cw + (pi << npacksh);      // pass channel base
            const float* pl = features + ((size_t)b * C_ + chb + hc) * S_;

            float cm[PH];
            #pragma unroll
            for (int pp = 0; pp < PH; ++pp) cm[pp] = -INFINITY;

            #pragma unroll
            for (int pp = 0; pp < PH; ++pp) {          // scalar band bounds
                const int sh = y1 + (pp * h) / PH;
                const int eh = y1 + ((pp + 1) * h + PH - 1) / PH;
                const float* prow = pl + sh * W_ + xcol;
                int n = eh - sh;
                if (n & 1) { cm[pp] = fmaxf(cm[pp], *prow); prow += W_; --n; }
                for (; n > 0; n -= 2, prow += 2 * W_)
                    cm[pp] = fmaxf(cm[pp], fmaxf(prow[0], prow[W_]));
            }

            #pragma unroll
            for (int pp = 0; pp < PH; ++pp)            // lane-linear writes
                strip[wid][pp][lane] = cm[pp];
            asm volatile("s_waitcnt lgkmcnt(0)" ::: "memory");   // x-lane RAW
            __builtin_amdgcn_sched_barrier(0);         // rule-18 fence

            #pragma unroll
            for (int hc2 = 0; hc2 < 4; ++hc2) {        // reduce pass channels
                if (hc2 < npack && lane < NCELL) {
                    const float* cb2 = &strip[wid][p][(hc2 << ncolsh) + swr];
                    float m = -INFINITY;
                    for (int k = 0; k < kmax; ++k)     // scalar bound, clamped
                        m = fmaxf(m, cb2[min(k, kwm1)]);
                    out[((size_t)r * C_ + chb + hc2) * NCELL + lane] = m;
                }
            }
            asm volatile("" ::: "memory");
            __builtin_amdgcn_sched_barrier(0);
        }
        asm volatile("" ::: "memory");                 // block cross-rep CSE
    }
}

extern "C" void kernel_launch(void* const* d_in, const int* in_sizes, int n_in,
                              void* d_out, int out_size, void* d_ws, size_t ws_size,
                              hipStream_t stream) {
    const float* features = (const float*)d_in[0];
    const int*   rois     = (const int*)d_in[1];
    float*       out      = (float*)d_out;
    (void)d_ws; (void)ws_size;

    roi_pool_pack4<<<R_ * 16, 256, 0, stream>>>(features, rois, out);
}

// Round 20
// 81.351 us; speedup vs baseline: 1.3906x; 1.3906x over previous
//
#include <hip/hip_runtime.h>
#include <math.h>

#define PH 7
#define PW 7
#define B_ 4
#define C_ 256
#define H_ 50
#define W_ 50
#define R_ 256
#define S_ (H_ * W_)     // 2500
#define NCELL (PH * PW)  // 49
#define SSTR 65          // strip row stride: (p*65)%32 = p -> p-groups on
                         // distinct banks (R19 counter: 5.07M conflicts @64)

// SINGLE dispatch, direct (B,C,H,W). R18 pack4 + two counter-driven fixes:
// (1) strip stride 64->65: kills the 7-way p-group bank conflict in the
//     reduce phase (R19: SQ_LDS_BANK_CONFLICT 5.07M -> expect <0.5M);
// (2) paired-band walk: bands (0,1)(2,3)(4,5) processed concurrently with
//     2-row steps each = 4 loads in flight (was 2); band 6 alone. Row
//     clamp min(i,n-1) is wave-uniform scalar; dup reads max-safe.
// Everything else proven in R16-R18: adaptive 4/2/1-channel packing by roi
// width, scalar band bounds, clamped dup cols, wave-private strip,
// lgkmcnt+sched_barrier fences, 196 B contiguous stores.
__global__ void __launch_bounds__(256, 8)
roi_pool_pack4(const float* __restrict__ features, const int* __restrict__ rois,
               float* __restrict__ out) {
    __shared__ float strip[4][PH][SSTR];  // wave-private strips, 7280 B
    const int bx   = blockIdx.x;
    const int r    = bx >> 4;             // 0..255
    const int wid  = threadIdx.x >> 6;    // 0..3
    const int lane = threadIdx.x & 63;
    const int cw   = ((bx & 15) << 4) | (wid << 2);   // wave's 4-ch base

    const int* roi = rois + r * 5;        // r uniform -> scalar loads
    const int b  = roi[0];
    const int x1 = roi[1] >> 4;           // floor(v/16), v in [0,800)
    const int y1 = roi[2] >> 4;
    const int x2 = roi[3] >> 4;
    const int y2 = roi[4] >> 4;
    const int h = y2 - y1 + 1;            // 1..50
    const int w = x2 - x1 + 1;            // 1..50

    // adaptive packing (all wave-uniform scalars)
    const int npacksh = (w <= 16) ? 2 : (w <= 32) ? 1 : 0;
    const int npack   = 1 << npacksh;     // 4 / 2 / 1 channels per pass
    const int ncolsh  = 6 - npacksh;      // 16 / 32 / 64 cols per channel
    const int ncol    = 1 << ncolsh;
    const int passes  = 4 >> npacksh;     // 1 / 2 / 4

    const int hc   = lane >> ncolsh;      // sub-channel within pass
    const int col  = lane & (ncol - 1);
    const int xcol = x1 + min(col, w - 1);   // clamped dup: max-safe, merged

    // reduce-phase lane mapping (lanes 49..63 idle there)
    const int cell = (lane < NCELL) ? lane : NCELL - 1;
    const int p  = cell / PW;             // magic mul
    const int q  = cell - p * PW;
    const int swr  = (q * w) / PW;
    const int ewr  = ((q + 1) * w + PW - 1) / PW;
    const int kwm1 = ewr - swr - 1;       // >= 0
    const int kmax = w / PW + 2;          // scalar bound, covers all windows

    #pragma unroll 1
    for (int pi = 0; pi < passes; ++pi) {
        const int chb = cw + (pi << npacksh);      // pass channel base
        const float* pl = features + ((size_t)b * C_ + chb + hc) * S_;

        float cm[PH];

        // paired bands (pA,pB): 4 independent loads in flight per iteration
        #pragma unroll
        for (int pb = 0; pb < 3; ++pb) {
            const int pA = 2 * pb, pB = 2 * pb + 1;
            const int shA = y1 + (pA * h) / PH;
            const int nA  = y1 + ((pA + 1) * h + PH - 1) / PH - shA;  // >=1
            const int shB = y1 + (pB * h) / PH;
            const int nB  = y1 + ((pB + 1) * h + PH - 1) / PH - shB;  // >=1
            const int n   = max(nA, nB);           // nA,nB differ by <=1
            const float* rA = pl + shA * W_ + xcol;
            const float* rB = pl + shB * W_ + xcol;
            float cA = -INFINITY, cB = -INFINITY;
            int i = 0;
            if (n & 1) {                           // rows 0 valid for both
                cA = fmaxf(cA, rA[0]);
                cB = fmaxf(cB, rB[0]);
                ++i;
            }
            for (; i < n; i += 2) {                // scalar row clamps
                const float a0 = rA[min(i,     nA - 1) * W_];
                const float a1 = rA[min(i + 1, nA - 1) * W_];
                const float b0 = rB[min(i,     nB - 1) * W_];
                const float b1 = rB[min(i + 1, nB - 1) * W_];
                cA = fmaxf(cA, fmaxf(a0, a1));
                cB = fmaxf(cB, fmaxf(b0, b1));
            }
            cm[pA] = cA; cm[pB] = cB;
        }
        {   // band 6 alone (2-row steps, proven loop)
            const int sh = y1 + (6 * h) / PH;
            const int eh = y1 + h;                 // y2+1
            const float* prow = pl + sh * W_ + xcol;
            int n = eh - sh;
            float c6 = -INFINITY;
            if (n & 1) { c6 = fmaxf(c6, *prow); prow += W_; --n; }
            for (; n > 0; n -= 2, prow += 2 * W_)
                c6 = fmaxf(c6, fmaxf(prow[0], prow[W_]));
            cm[6] = c6;
        }

        #pragma unroll
        for (int pp = 0; pp < PH; ++pp)            // lane-linear: 2-way, free
            strip[wid][pp][lane] = cm[pp];
        asm volatile("s_waitcnt lgkmcnt(0)" ::: "memory");   // cross-lane RAW
        __builtin_amdgcn_sched_barrier(0);         // rule-18 fence

        #pragma unroll
        for (int hc2 = 0; hc2 < 4; ++hc2) {        // reduce pass channels
            if (hc2 < npack && lane < NCELL) {
                const float* cb2 = &strip[wid][p][(hc2 << ncolsh) + swr];
                float m = -INFINITY;
                for (int k = 0; k < kmax; ++k)     // scalar bound, clamped
                    m = fmaxf(m, cb2[min(k, kwm1)]);
                out[((size_t)r * C_ + chb + hc2) * NCELL + lane] = m;
            }
        }
        // keep next pass's strip writes after this pass's reads
        asm volatile("" ::: "memory");
        __builtin_amdgcn_sched_barrier(0);
    }
}

extern "C" void kernel_launch(void* const* d_in, const int* in_sizes, int n_in,
                              void* d_out, int out_size, void* d_ws, size_t ws_size,
                              hipStream_t stream) {
    const float* features = (const float*)d_in[0];
    const int*   rois     = (const int*)d_in[1];
    float*       out      = (float*)d_out;
    (void)d_ws; (void)ws_size;

    roi_pool_pack4<<<R_ * 16, 256, 0, stream>>>(features, rois, out);
}